// Round 5
// baseline (430.315 us; speedup 1.0000x reference)
//
#include <hip/hip_runtime.h>

#define N_NODES 100000
#define N_EDGES 1600000
#define NEG_SLOPE 0.2f

typedef __bf16 bf16x8 __attribute__((ext_vector_type(8)));
typedef float f32x4 __attribute__((ext_vector_type(4)));
typedef _Float16 f16x4 __attribute__((ext_vector_type(4)));

__device__ inline unsigned short f2bf(float f) {
    union { float f; unsigned u; } x; x.f = f;
    unsigned r = x.u + 0x7fffu + ((x.u >> 16) & 1u);   // round-to-nearest-even
    return (unsigned short)(r >> 16);
}

// ---- merged prep: cvt_w (512 blk) | cvt_wa (16 blk) | rowptr (391 blk) -----
// Bodies verbatim from the validated kernels; fused to cut 2 launches.
__global__ __launch_bounds__(256) void prep_k(const float* __restrict__ Ws,
                                              const float* __restrict__ Wd,
                                              const float* __restrict__ Was,
                                              const float* __restrict__ Wad,
                                              const int* __restrict__ dst,
                                              unsigned short* __restrict__ Wsw_src,
                                              unsigned short* __restrict__ Wsw_dst,
                                              unsigned short* __restrict__ Wa_sw,
                                              int* __restrict__ rp) {
    int b = blockIdx.x;
    if (b < 512) {
        // W_src / W_dst -> bf16, MFMA B-fragment order
        // (k,n): lane = ((k&31)>>3)*16 + (n&15), j = k&7; [ct(16)][ks(8)][lane][j]
        int idx = b * 256 + threadIdx.x;             // 0..131071
        int sel = idx >> 16;
        int r = idx & 65535;
        int k = r >> 8, n = r & 255;
        int ct = n >> 4, nl = n & 15;
        int lane = ((k & 31) >> 3) * 16 + nl, j = k & 7;
        int ks = k >> 5;
        unsigned short v = f2bf((sel == 0 ? Ws : Wd)[k * 256 + n]);
        (sel == 0 ? Wsw_src : Wsw_dst)[(ct * 8 + ks) * 512 + lane * 8 + j] = v;
    } else if (b < 528) {
        // [Wa_src|Wa_dst|0] -> bf16 B-fragment [ks(8)][lane(64)][j(8)]
        int idx = (b - 512) * 256 + threadIdx.x;     // 0..4095
        int j = idx & 7, lane = (idx >> 3) & 63, ks = idx >> 9;
        int n = lane & 15, k = ks * 32 + (lane >> 4) * 8 + j;
        float v = n < 4 ? Was[k * 4 + n] : (n < 8 ? Wad[k * 4 + (n - 4)] : 0.f);
        Wa_sw[idx] = f2bf(v);
    } else {
        // CSR row pointers from sorted dst
        int n = (b - 528) * 256 + threadIdx.x;
        if (n > N_NODES) return;
        int lo = 0, hi = N_EDGES;                    // first i with dst[i] >= n
        while (lo < hi) { int mid = (lo + hi) >> 1; if (dst[mid] < n) lo = mid + 1; else hi = mid; }
        rp[n] = lo;
    }
}

// ---- attention logits via the R0-VALIDATED kernel (f16 stores) -------------
// R3 diagnostics: fused acca logits in proj were WRONG (chka); this kernel's
// logits validated end-to-end in R0/R4. Do not re-fuse.
__global__ __launch_bounds__(256) void aproj_k(const float* __restrict__ feat,
                                               const unsigned short* __restrict__ Wa_sw,
                                               _Float16* __restrict__ a_srcH,
                                               _Float16* __restrict__ a_dstH) {
    int wave = threadIdx.x >> 6, lane = threadIdx.x & 63;
    int quad = lane >> 4, l16 = lane & 15;
    int row_strip = (blockIdx.x * 4 + wave) * 16;
    int arow = row_strip + l16;
    if (arow >= N_NODES) arow = N_NODES - 1;         // clamp loads; stores guarded
    const float* arow_p = feat + (size_t)arow * 256;
    const bf16x8* Wa8 = (const bf16x8*)Wa_sw;
    f32x4 acc = {0.f, 0.f, 0.f, 0.f};
    #pragma unroll
    for (int ks = 0; ks < 8; ++ks) {
        int k0 = ks * 32 + quad * 8;
        float4 f0 = *(const float4*)(arow_p + k0);
        float4 f1 = *(const float4*)(arow_p + k0 + 4);
        union { unsigned short u[8]; bf16x8 v; } cv;
        cv.u[0] = f2bf(f0.x); cv.u[1] = f2bf(f0.y);
        cv.u[2] = f2bf(f0.z); cv.u[3] = f2bf(f0.w);
        cv.u[4] = f2bf(f1.x); cv.u[5] = f2bf(f1.y);
        cv.u[6] = f2bf(f1.z); cv.u[7] = f2bf(f1.w);
        acc = __builtin_amdgcn_mfma_f32_16x16x32_bf16(cv.v, Wa8[ks * 64 + lane], acc, 0, 0, 0);
    }
    #pragma unroll
    for (int r = 0; r < 4; ++r) {                    // row = quad*4+r, col = l16
        int n = row_strip + quad * 4 + r;
        if (n < N_NODES) {
            if (l16 < 4)      a_srcH[(size_t)n * 4 + l16] = (_Float16)acc[r];
            else if (l16 < 8) a_dstH[(size_t)n * 4 + (l16 - 4)] = (_Float16)acc[r];
        }
    }
}

// ---- projection GEMM: M=100000, K=256; waves 0-3: h_src (f16), 4-7: h_dst --
// Validated in R3 (chkh clean) / R4 (end-to-end pass).
__global__ __launch_bounds__(512) void proj_k(const float* __restrict__ feat,
                                              const unsigned short* __restrict__ Wsw_src,
                                              const unsigned short* __restrict__ Wsw_dst,
                                              const float* __restrict__ b_dst,
                                              _Float16* __restrict__ h_src,
                                              float* __restrict__ out) {
    __shared__ unsigned short F[4 * 32 * 17 * 8];    // 34,816 B
    int tid = threadIdx.x, wave = tid >> 6, lane = tid & 63;
    int quad = lane >> 4, l16 = lane & 15;
    int base = blockIdx.x * 64;

    #pragma unroll
    for (int it = 0; it < 8; ++it) {
        int c = tid + it * 512;
        int m = c >> 6, k0 = (c & 63) * 4;
        int row = base + m; if (row > N_NODES - 1) row = N_NODES - 1;
        float4 f = *(const float4*)(feat + (size_t)row * 256 + k0);
        ushort4 u;
        u.x = f2bf(f.x); u.y = f2bf(f.y); u.z = f2bf(f.z); u.w = f2bf(f.w);
        int strip = m >> 4, ms = m & 15, kq = k0 >> 3, jb = k0 & 7;
        *(ushort4*)&F[((strip * 32 + kq) * 17 + ms) * 8 + jb] = u;
    }
    __syncthreads();

    bool isSrc = wave < 4;
    int cg = (wave & 3) * 4;
    const bf16x8* W8 = (const bf16x8*)(isSrc ? Wsw_src : Wsw_dst);

    f32x4 acc[4][4];
    #pragma unroll
    for (int s = 0; s < 4; ++s)
        #pragma unroll
        for (int c = 0; c < 4; ++c) acc[s][c] = (f32x4){0.f, 0.f, 0.f, 0.f};

    #pragma unroll
    for (int ks = 0; ks < 8; ++ks) {
        bf16x8 B0 = W8[((cg + 0) * 8 + ks) * 64 + lane];
        bf16x8 B1 = W8[((cg + 1) * 8 + ks) * 64 + lane];
        bf16x8 B2 = W8[((cg + 2) * 8 + ks) * 64 + lane];
        bf16x8 B3 = W8[((cg + 3) * 8 + ks) * 64 + lane];
        #pragma unroll
        for (int s = 0; s < 4; ++s) {
            bf16x8 A = *(const bf16x8*)&F[((s * 32 + ks * 4 + quad) * 17 + l16) * 8];
            acc[s][0] = __builtin_amdgcn_mfma_f32_16x16x32_bf16(A, B0, acc[s][0], 0, 0, 0);
            acc[s][1] = __builtin_amdgcn_mfma_f32_16x16x32_bf16(A, B1, acc[s][1], 0, 0, 0);
            acc[s][2] = __builtin_amdgcn_mfma_f32_16x16x32_bf16(A, B2, acc[s][2], 0, 0, 0);
            acc[s][3] = __builtin_amdgcn_mfma_f32_16x16x32_bf16(A, B3, acc[s][3], 0, 0, 0);
        }
    }

    if (isSrc) {
        #pragma unroll
        for (int s = 0; s < 4; ++s)
            #pragma unroll
            for (int c = 0; c < 4; ++c) {
                int col = (cg + c) * 16 + l16;
                #pragma unroll
                for (int r = 0; r < 4; ++r) {
                    int row = base + s * 16 + quad * 4 + r;
                    if (row < N_NODES)
                        h_src[(size_t)row * 256 + col] = (_Float16)acc[s][c][r];
                }
            }
    } else {
        #pragma unroll
        for (int c = 0; c < 4; ++c) {
            int col = (cg + c) * 16 + l16;
            float b = b_dst[col];
            #pragma unroll
            for (int s = 0; s < 4; ++s)
                #pragma unroll
                for (int r = 0; r < 4; ++r) {
                    int row = base + s * 16 + quad * 4 + r;
                    if (row < N_NODES)
                        out[(size_t)row * 256 + col] = acc[s][c][r] + b;
                }
        }
    }
}

// ---- h-space aggregation: one wave per node, no barrier, no MFMA -----------
// R5 changes vs validated R4 body: (a) launch_bounds 6->8 blocks/CU (was the
// 76% occupancy cap; VGPR=24 leaves headroom), (b) gather unrolled 8-deep
// (8 row-loads in flight vs 4 — latency-bound per R4 counters: VALU 53%,
// HBM 50%, nothing saturated). Math/dataflow unchanged.
__global__ __launch_bounds__(256, 8) void agg2_k(const int* __restrict__ src,
                                                 const int* __restrict__ rp,
                                                 const _Float16* __restrict__ a_srcH,
                                                 const _Float16* __restrict__ a_dstH,
                                                 const _Float16* __restrict__ h_src,
                                                 float* __restrict__ out) {
    __shared__ float WT[4][64][4];
    int tid = threadIdx.x, wave = tid >> 6, lane = tid & 63;
    int node = blockIdx.x * 4 + wave;                // grid covers exactly N_NODES
    int head = lane >> 4;                            // lane owns cols lane*4..+3
    int r0 = rp[node], r1 = rp[node + 1], deg = r1 - r0;

    size_t o = (size_t)node * 256 + lane * 4;
    float4 pv = *(const float4*)(out + o);           // h_dst (from proj_k)

    f32x4 g = (f32x4){0.f, 0.f, 0.f, 0.f};
    const _Float16* hl = h_src + lane * 4;

    if (deg > 0 && deg <= 64) {
        f16x4 adv4 = *(const f16x4*)(a_dstH + (size_t)node * 4);
        float ad0 = (float)adv4[0], ad1 = (float)adv4[1];
        float ad2 = (float)adv4[2], ad3 = (float)adv4[3];
        bool act = lane < deg;
        int s = 0;
        f16x4 av4 = (f16x4){0, 0, 0, 0};
        if (act) {
            s = src[r0 + lane];
            av4 = *(const f16x4*)(a_srcH + (size_t)s * 4);
        }
        float e0 = (float)av4[0] + ad0; e0 = e0 > 0.f ? e0 : NEG_SLOPE * e0;
        float e1 = (float)av4[1] + ad1; e1 = e1 > 0.f ? e1 : NEG_SLOPE * e1;
        float e2 = (float)av4[2] + ad2; e2 = e2 > 0.f ? e2 : NEG_SLOPE * e2;
        float e3 = (float)av4[3] + ad3; e3 = e3 > 0.f ? e3 : NEG_SLOPE * e3;
        if (!act) { e0 = e1 = e2 = e3 = -1e30f; }
        float m0 = e0, m1 = e1, m2 = e2, m3 = e3;
        for (int off = 1; off < deg; off <<= 1) {    // adaptive butterfly
            m0 = fmaxf(m0, __shfl_xor(m0, off));
            m1 = fmaxf(m1, __shfl_xor(m1, off));
            m2 = fmaxf(m2, __shfl_xor(m2, off));
            m3 = fmaxf(m3, __shfl_xor(m3, off));
        }
        float w0 = act ? __expf(e0 - m0) : 0.f;
        float w1 = act ? __expf(e1 - m1) : 0.f;
        float w2 = act ? __expf(e2 - m2) : 0.f;
        float w3 = act ? __expf(e3 - m3) : 0.f;
        float d0 = w0, d1 = w1, d2 = w2, d3 = w3;
        for (int off = 1; off < deg; off <<= 1) {
            d0 += __shfl_xor(d0, off); d1 += __shfl_xor(d1, off);
            d2 += __shfl_xor(d2, off); d3 += __shfl_xor(d3, off);
        }
        w0 *= 1.f / d0; w1 *= 1.f / d1; w2 *= 1.f / d2; w3 *= 1.f / d3;
        float4 wv; wv.x = w0; wv.y = w1; wv.z = w2; wv.w = w3;
        *(float4*)&WT[wave][lane][0] = wv;           // same-wave LDS transpose
        asm volatile("s_waitcnt lgkmcnt(0)" ::: "memory");

        int j = 0;
        for (; j + 8 <= deg; j += 8) {               // 8 row-loads in flight
            int s0 = __builtin_amdgcn_readlane(s, j);
            int s1 = __builtin_amdgcn_readlane(s, j + 1);
            int s2 = __builtin_amdgcn_readlane(s, j + 2);
            int s3 = __builtin_amdgcn_readlane(s, j + 3);
            int s4 = __builtin_amdgcn_readlane(s, j + 4);
            int s5 = __builtin_amdgcn_readlane(s, j + 5);
            int s6 = __builtin_amdgcn_readlane(s, j + 6);
            int s7 = __builtin_amdgcn_readlane(s, j + 7);
            f16x4 h0 = *(const f16x4*)(hl + (size_t)s0 * 256);
            f16x4 h1 = *(const f16x4*)(hl + (size_t)s1 * 256);
            f16x4 h2 = *(const f16x4*)(hl + (size_t)s2 * 256);
            f16x4 h3 = *(const f16x4*)(hl + (size_t)s3 * 256);
            f16x4 h4 = *(const f16x4*)(hl + (size_t)s4 * 256);
            f16x4 h5 = *(const f16x4*)(hl + (size_t)s5 * 256);
            f16x4 h6 = *(const f16x4*)(hl + (size_t)s6 * 256);
            f16x4 h7 = *(const f16x4*)(hl + (size_t)s7 * 256);
            float x0 = WT[wave][j][head],     x1 = WT[wave][j + 1][head];
            float x2 = WT[wave][j + 2][head], x3 = WT[wave][j + 3][head];
            float x4 = WT[wave][j + 4][head], x5 = WT[wave][j + 5][head];
            float x6 = WT[wave][j + 6][head], x7 = WT[wave][j + 7][head];
            g[0] += x0 * (float)h0[0]; g[1] += x0 * (float)h0[1];
            g[2] += x0 * (float)h0[2]; g[3] += x0 * (float)h0[3];
            g[0] += x1 * (float)h1[0]; g[1] += x1 * (float)h1[1];
            g[2] += x1 * (float)h1[2]; g[3] += x1 * (float)h1[3];
            g[0] += x2 * (float)h2[0]; g[1] += x2 * (float)h2[1];
            g[2] += x2 * (float)h2[2]; g[3] += x2 * (float)h2[3];
            g[0] += x3 * (float)h3[0]; g[1] += x3 * (float)h3[1];
            g[2] += x3 * (float)h3[2]; g[3] += x3 * (float)h3[3];
            g[0] += x4 * (float)h4[0]; g[1] += x4 * (float)h4[1];
            g[2] += x4 * (float)h4[2]; g[3] += x4 * (float)h4[3];
            g[0] += x5 * (float)h5[0]; g[1] += x5 * (float)h5[1];
            g[2] += x5 * (float)h5[2]; g[3] += x5 * (float)h5[3];
            g[0] += x6 * (float)h6[0]; g[1] += x6 * (float)h6[1];
            g[2] += x6 * (float)h6[2]; g[3] += x6 * (float)h6[3];
            g[0] += x7 * (float)h7[0]; g[1] += x7 * (float)h7[1];
            g[2] += x7 * (float)h7[2]; g[3] += x7 * (float)h7[3];
        }
        for (; j + 4 <= deg; j += 4) {
            int s0 = __builtin_amdgcn_readlane(s, j);
            int s1 = __builtin_amdgcn_readlane(s, j + 1);
            int s2 = __builtin_amdgcn_readlane(s, j + 2);
            int s3 = __builtin_amdgcn_readlane(s, j + 3);
            f16x4 h0 = *(const f16x4*)(hl + (size_t)s0 * 256);
            f16x4 h1 = *(const f16x4*)(hl + (size_t)s1 * 256);
            f16x4 h2 = *(const f16x4*)(hl + (size_t)s2 * 256);
            f16x4 h3 = *(const f16x4*)(hl + (size_t)s3 * 256);
            float x0 = WT[wave][j][head],     x1 = WT[wave][j + 1][head];
            float x2 = WT[wave][j + 2][head], x3 = WT[wave][j + 3][head];
            g[0] += x0 * (float)h0[0]; g[1] += x0 * (float)h0[1];
            g[2] += x0 * (float)h0[2]; g[3] += x0 * (float)h0[3];
            g[0] += x1 * (float)h1[0]; g[1] += x1 * (float)h1[1];
            g[2] += x1 * (float)h1[2]; g[3] += x1 * (float)h1[3];
            g[0] += x2 * (float)h2[0]; g[1] += x2 * (float)h2[1];
            g[2] += x2 * (float)h2[2]; g[3] += x2 * (float)h2[3];
            g[0] += x3 * (float)h3[0]; g[1] += x3 * (float)h3[1];
            g[2] += x3 * (float)h3[2]; g[3] += x3 * (float)h3[3];
        }
        for (; j < deg; ++j) {
            int sj = __builtin_amdgcn_readlane(s, j);
            float xj = WT[wave][j][head];
            f16x4 h = *(const f16x4*)(hl + (size_t)sj * 256);
            g[0] += xj * (float)h[0]; g[1] += xj * (float)h[1];
            g[2] += xj * (float)h[2]; g[3] += xj * (float)h[3];
        }
    } else if (deg > 64) {
        // ---- fallback: chunked 3-pass (deg ~ Poisson(16); essentially never) ----
        f16x4 adv4 = *(const f16x4*)(a_dstH + (size_t)node * 4);
        float ad0 = (float)adv4[0], ad1 = (float)adv4[1];
        float ad2 = (float)adv4[2], ad3 = (float)adv4[3];
        float m0 = -1e30f, m1 = -1e30f, m2 = -1e30f, m3 = -1e30f;
        for (int e = r0 + lane; e < r1; e += 64) {
            int se = src[e];
            f16x4 av4 = *(const f16x4*)(a_srcH + (size_t)se * 4);
            float e0 = (float)av4[0] + ad0; e0 = e0 > 0.f ? e0 : NEG_SLOPE * e0;
            float e1 = (float)av4[1] + ad1; e1 = e1 > 0.f ? e1 : NEG_SLOPE * e1;
            float e2 = (float)av4[2] + ad2; e2 = e2 > 0.f ? e2 : NEG_SLOPE * e2;
            float e3 = (float)av4[3] + ad3; e3 = e3 > 0.f ? e3 : NEG_SLOPE * e3;
            m0 = fmaxf(m0, e0); m1 = fmaxf(m1, e1);
            m2 = fmaxf(m2, e2); m3 = fmaxf(m3, e3);
        }
        #pragma unroll
        for (int off = 32; off > 0; off >>= 1) {
            m0 = fmaxf(m0, __shfl_xor(m0, off)); m1 = fmaxf(m1, __shfl_xor(m1, off));
            m2 = fmaxf(m2, __shfl_xor(m2, off)); m3 = fmaxf(m3, __shfl_xor(m3, off));
        }
        float d0 = 0.f, d1 = 0.f, d2 = 0.f, d3 = 0.f;
        for (int e = r0 + lane; e < r1; e += 64) {
            int se = src[e];
            f16x4 av4 = *(const f16x4*)(a_srcH + (size_t)se * 4);
            float e0 = (float)av4[0] + ad0; e0 = e0 > 0.f ? e0 : NEG_SLOPE * e0;
            float e1 = (float)av4[1] + ad1; e1 = e1 > 0.f ? e1 : NEG_SLOPE * e1;
            float e2 = (float)av4[2] + ad2; e2 = e2 > 0.f ? e2 : NEG_SLOPE * e2;
            float e3 = (float)av4[3] + ad3; e3 = e3 > 0.f ? e3 : NEG_SLOPE * e3;
            d0 += __expf(e0 - m0); d1 += __expf(e1 - m1);
            d2 += __expf(e2 - m2); d3 += __expf(e3 - m3);
        }
        #pragma unroll
        for (int off = 32; off > 0; off >>= 1) {
            d0 += __shfl_xor(d0, off); d1 += __shfl_xor(d1, off);
            d2 += __shfl_xor(d2, off); d3 += __shfl_xor(d3, off);
        }
        float i0 = 1.f / d0, i1 = 1.f / d1, i2 = 1.f / d2, i3 = 1.f / d3;
        for (int c0 = r0; c0 < r1; c0 += 64) {
            int cnt = min(64, r1 - c0);
            int s = 0; float w0 = 0.f, w1 = 0.f, w2 = 0.f, w3 = 0.f;
            if (lane < cnt) {
                s = src[c0 + lane];
                f16x4 av4 = *(const f16x4*)(a_srcH + (size_t)s * 4);
                float e0 = (float)av4[0] + ad0; e0 = e0 > 0.f ? e0 : NEG_SLOPE * e0;
                float e1 = (float)av4[1] + ad1; e1 = e1 > 0.f ? e1 : NEG_SLOPE * e1;
                float e2 = (float)av4[2] + ad2; e2 = e2 > 0.f ? e2 : NEG_SLOPE * e2;
                float e3 = (float)av4[3] + ad3; e3 = e3 > 0.f ? e3 : NEG_SLOPE * e3;
                w0 = __expf(e0 - m0) * i0; w1 = __expf(e1 - m1) * i1;
                w2 = __expf(e2 - m2) * i2; w3 = __expf(e3 - m3) * i3;
            }
            float4 wv; wv.x = w0; wv.y = w1; wv.z = w2; wv.w = w3;
            *(float4*)&WT[wave][lane][0] = wv;
            asm volatile("s_waitcnt lgkmcnt(0)" ::: "memory");
            for (int j = 0; j < cnt; ++j) {
                int sj = __builtin_amdgcn_readlane(s, j);
                float xj = WT[wave][j][head];
                f16x4 h = *(const f16x4*)(hl + (size_t)sj * 256);
                g[0] += xj * (float)h[0]; g[1] += xj * (float)h[1];
                g[2] += xj * (float)h[2]; g[3] += xj * (float)h[3];
            }
        }
    }
    float4 res;
    res.x = pv.x + g[0]; res.y = pv.y + g[1];
    res.z = pv.z + g[2]; res.w = pv.w + g[3];
    *(float4*)(out + o) = res;
}

extern "C" void kernel_launch(void* const* d_in, const int* in_sizes, int n_in,
                              void* d_out, int out_size, void* d_ws, size_t ws_size,
                              hipStream_t stream) {
    const float* feat   = (const float*)d_in[0];
    const float* W_src  = (const float*)d_in[1];
    const float* W_dst  = (const float*)d_in[2];
    const float* b_dst  = (const float*)d_in[3];
    const float* Wa_src = (const float*)d_in[4];
    const float* Wa_dst = (const float*)d_in[5];
    const int*   src    = (const int*)d_in[6];
    const int*   dst    = (const int*)d_in[7];
    float* out = (float*)d_out;
    char* ws = (char*)d_ws;

    // 53,470,340 B total — proven to fit (R2 ran Tier L; R4 passed with this).
    _Float16* h_srcH        = (_Float16*)(ws);                     // 51,200,000
    unsigned short* Wsw_src = (unsigned short*)(ws + 51200000);    //    131,072
    unsigned short* Wsw_dst = (unsigned short*)(ws + 51331072);    //    131,072
    unsigned short* Wa_sw   = (unsigned short*)(ws + 51462144);    //      8,192
    _Float16* a_srcH        = (_Float16*)(ws + 51470336);          //    800,000
    _Float16* a_dstH        = (_Float16*)(ws + 52270336);          //    800,000
    int*      rp            = (int*)(ws + 53070336);               //    400,004

    hipLaunchKernelGGL(prep_k,  dim3(919),   dim3(256), 0, stream, W_src, W_dst, Wa_src, Wa_dst,
                       dst, Wsw_src, Wsw_dst, Wa_sw, rp);
    hipLaunchKernelGGL(aproj_k, dim3(1563),  dim3(256), 0, stream, feat, Wa_sw, a_srcH, a_dstH);
    hipLaunchKernelGGL(proj_k,  dim3(1563),  dim3(512), 0, stream, feat, Wsw_src, Wsw_dst,
                       b_dst, h_srcH, out);
    hipLaunchKernelGGL(agg2_k,  dim3(25000), dim3(256), 0, stream, src, rp, a_srcH, a_dstH,
                       h_srcH, out);
}

// Round 6
// 393.667 us; speedup vs baseline: 1.0931x; 1.0931x over previous
//
#include <hip/hip_runtime.h>

#define N_NODES 100000
#define N_EDGES 1600000
#define NEG_SLOPE 0.2f

typedef __bf16 bf16x8 __attribute__((ext_vector_type(8)));
typedef float f32x4 __attribute__((ext_vector_type(4)));
typedef _Float16 f16x4 __attribute__((ext_vector_type(4)));

__device__ inline unsigned short f2bf(float f) {
    union { float f; unsigned u; } x; x.f = f;
    unsigned r = x.u + 0x7fffu + ((x.u >> 16) & 1u);   // round-to-nearest-even
    return (unsigned short)(r >> 16);
}

// ---- merged prep: cvt_w (512 blk) | cvt_wa (16 blk) | rowptr (391 blk) -----
__global__ __launch_bounds__(256) void prep_k(const float* __restrict__ Ws,
                                              const float* __restrict__ Wd,
                                              const float* __restrict__ Was,
                                              const float* __restrict__ Wad,
                                              const int* __restrict__ dst,
                                              unsigned short* __restrict__ Wsw_src,
                                              unsigned short* __restrict__ Wsw_dst,
                                              unsigned short* __restrict__ Wa_sw,
                                              int* __restrict__ rp) {
    int b = blockIdx.x;
    if (b < 512) {
        // W_src / W_dst -> bf16, MFMA B-fragment order (validated)
        int idx = b * 256 + threadIdx.x;             // 0..131071
        int sel = idx >> 16;
        int r = idx & 65535;
        int k = r >> 8, n = r & 255;
        int ct = n >> 4, nl = n & 15;
        int lane = ((k & 31) >> 3) * 16 + nl, j = k & 7;
        int ks = k >> 5;
        unsigned short v = f2bf((sel == 0 ? Ws : Wd)[k * 256 + n]);
        (sel == 0 ? Wsw_src : Wsw_dst)[(ct * 8 + ks) * 512 + lane * 8 + j] = v;
    } else if (b < 528) {
        // [Wa_src|Wa_dst|0] -> bf16 B-fragment [ks(8)][lane(64)][j(8)]
        int idx = (b - 512) * 256 + threadIdx.x;     // 0..4095
        int j = idx & 7, lane = (idx >> 3) & 63, ks = idx >> 9;
        int n = lane & 15, k = ks * 32 + (lane >> 4) * 8 + j;
        float v = n < 4 ? Was[k * 4 + n] : (n < 8 ? Wad[k * 4 + (n - 4)] : 0.f);
        Wa_sw[idx] = f2bf(v);
    } else {
        // CSR row pointers from sorted dst
        int n = (b - 528) * 256 + threadIdx.x;
        if (n > N_NODES) return;
        int lo = 0, hi = N_EDGES;                    // first i with dst[i] >= n
        while (lo < hi) { int mid = (lo + hi) >> 1; if (dst[mid] < n) lo = mid + 1; else hi = mid; }
        rp[n] = lo;
    }
}

// ---- fused projection: blocks [0,1563) = proj GEMM; [1563,2345) = aproj ----
// proj body validated R3/R4; aproj body is the R0-validated logit kernel with
// strip = (b-1563)*8 + wave (per-wave independent; only indexing changed).
// Block-level fusion only — the R1 wave-level acca fusion (proven wrong in R3)
// is NOT revisited.
__global__ __launch_bounds__(512) void proja_k(const float* __restrict__ feat,
                                               const unsigned short* __restrict__ Wsw_src,
                                               const unsigned short* __restrict__ Wsw_dst,
                                               const unsigned short* __restrict__ Wa_sw,
                                               const float* __restrict__ b_dst,
                                               _Float16* __restrict__ h_src,
                                               _Float16* __restrict__ h_dstH,
                                               int useHD,
                                               _Float16* __restrict__ a_srcH,
                                               _Float16* __restrict__ a_dstH,
                                               float* __restrict__ out) {
    __shared__ unsigned short F[4 * 32 * 17 * 8];    // 34,816 B (proj branch only)
    int tid = threadIdx.x, wave = tid >> 6, lane = tid & 63;
    int quad = lane >> 4, l16 = lane & 15;

    if (blockIdx.x >= 1563) {
        // ================== aproj branch (verbatim wave body) ==================
        int strip = (blockIdx.x - 1563) * 8 + wave;  // 6256 strips >= 6250 needed
        int row_strip = strip * 16;
        int arow = row_strip + l16;
        if (arow >= N_NODES) arow = N_NODES - 1;     // clamp loads; stores guarded
        const float* arow_p = feat + (size_t)arow * 256;
        const bf16x8* Wa8 = (const bf16x8*)Wa_sw;
        f32x4 acc = {0.f, 0.f, 0.f, 0.f};
        #pragma unroll
        for (int ks = 0; ks < 8; ++ks) {
            int k0 = ks * 32 + quad * 8;
            float4 f0 = *(const float4*)(arow_p + k0);
            float4 f1 = *(const float4*)(arow_p + k0 + 4);
            union { unsigned short u[8]; bf16x8 v; } cv;
            cv.u[0] = f2bf(f0.x); cv.u[1] = f2bf(f0.y);
            cv.u[2] = f2bf(f0.z); cv.u[3] = f2bf(f0.w);
            cv.u[4] = f2bf(f1.x); cv.u[5] = f2bf(f1.y);
            cv.u[6] = f2bf(f1.z); cv.u[7] = f2bf(f1.w);
            acc = __builtin_amdgcn_mfma_f32_16x16x32_bf16(cv.v, Wa8[ks * 64 + lane], acc, 0, 0, 0);
        }
        #pragma unroll
        for (int r = 0; r < 4; ++r) {                // row = quad*4+r, col = l16
            int n = row_strip + quad * 4 + r;
            if (n < N_NODES) {
                if (l16 < 4)      a_srcH[(size_t)n * 4 + l16] = (_Float16)acc[r];
                else if (l16 < 8) a_dstH[(size_t)n * 4 + (l16 - 4)] = (_Float16)acc[r];
            }
        }
        return;
    }

    // ====================== proj branch (verbatim) ==========================
    int base = blockIdx.x * 64;
    #pragma unroll
    for (int it = 0; it < 8; ++it) {
        int c = tid + it * 512;
        int m = c >> 6, k0 = (c & 63) * 4;
        int row = base + m; if (row > N_NODES - 1) row = N_NODES - 1;
        float4 f = *(const float4*)(feat + (size_t)row * 256 + k0);
        ushort4 u;
        u.x = f2bf(f.x); u.y = f2bf(f.y); u.z = f2bf(f.z); u.w = f2bf(f.w);
        int strip = m >> 4, ms = m & 15, kq = k0 >> 3, jb = k0 & 7;
        *(ushort4*)&F[((strip * 32 + kq) * 17 + ms) * 8 + jb] = u;
    }
    __syncthreads();

    bool isSrc = wave < 4;
    int cg = (wave & 3) * 4;
    const bf16x8* W8 = (const bf16x8*)(isSrc ? Wsw_src : Wsw_dst);

    f32x4 acc[4][4];
    #pragma unroll
    for (int s = 0; s < 4; ++s)
        #pragma unroll
        for (int c = 0; c < 4; ++c) acc[s][c] = (f32x4){0.f, 0.f, 0.f, 0.f};

    #pragma unroll
    for (int ks = 0; ks < 8; ++ks) {
        bf16x8 B0 = W8[((cg + 0) * 8 + ks) * 64 + lane];
        bf16x8 B1 = W8[((cg + 1) * 8 + ks) * 64 + lane];
        bf16x8 B2 = W8[((cg + 2) * 8 + ks) * 64 + lane];
        bf16x8 B3 = W8[((cg + 3) * 8 + ks) * 64 + lane];
        #pragma unroll
        for (int s = 0; s < 4; ++s) {
            bf16x8 A = *(const bf16x8*)&F[((s * 32 + ks * 4 + quad) * 17 + l16) * 8];
            acc[s][0] = __builtin_amdgcn_mfma_f32_16x16x32_bf16(A, B0, acc[s][0], 0, 0, 0);
            acc[s][1] = __builtin_amdgcn_mfma_f32_16x16x32_bf16(A, B1, acc[s][1], 0, 0, 0);
            acc[s][2] = __builtin_amdgcn_mfma_f32_16x16x32_bf16(A, B2, acc[s][2], 0, 0, 0);
            acc[s][3] = __builtin_amdgcn_mfma_f32_16x16x32_bf16(A, B3, acc[s][3], 0, 0, 0);
        }
    }

    if (isSrc) {
        #pragma unroll
        for (int s = 0; s < 4; ++s)
            #pragma unroll
            for (int c = 0; c < 4; ++c) {
                int col = (cg + c) * 16 + l16;
                #pragma unroll
                for (int r = 0; r < 4; ++r) {
                    int row = base + s * 16 + quad * 4 + r;
                    if (row < N_NODES)
                        h_src[(size_t)row * 256 + col] = (_Float16)acc[s][c][r];
                }
            }
    } else {
        #pragma unroll
        for (int c = 0; c < 4; ++c) {
            int col = (cg + c) * 16 + l16;
            float b = b_dst[col];
            #pragma unroll
            for (int s = 0; s < 4; ++s)
                #pragma unroll
                for (int r = 0; r < 4; ++r) {
                    int row = base + s * 16 + quad * 4 + r;
                    if (row < N_NODES) {
                        if (useHD) h_dstH[(size_t)row * 256 + col] = (_Float16)(acc[s][c][r] + b);
                        else       out[(size_t)row * 256 + col] = acc[s][c][r] + b;
                    }
                }
        }
    }
}

// ---- h-space aggregation: EXACT R4 body (147 µs) + optional f16 h_dst read -
// R5 lesson: 8-deep gather + (256,8) bounds thrashed L2 (FETCH +29 MB,
// WRITE +49 MB, dur +17 µs). Keep 4-deep, (256,6).
__global__ __launch_bounds__(256, 6) void agg2_k(const int* __restrict__ src,
                                                 const int* __restrict__ rp,
                                                 const _Float16* __restrict__ a_srcH,
                                                 const _Float16* __restrict__ a_dstH,
                                                 const _Float16* __restrict__ h_src,
                                                 const _Float16* __restrict__ h_dstH,
                                                 int useHD,
                                                 float* __restrict__ out) {
    __shared__ float WT[4][64][4];
    int tid = threadIdx.x, wave = tid >> 6, lane = tid & 63;
    int node = blockIdx.x * 4 + wave;                // grid covers exactly N_NODES
    int head = lane >> 4;                            // lane owns cols lane*4..+3
    int r0 = rp[node], r1 = rp[node + 1], deg = r1 - r0;

    size_t o = (size_t)node * 256 + lane * 4;
    float4 pv;
    if (useHD) {
        f16x4 hd = *(const f16x4*)(h_dstH + o);      // h_dst f16 (tier big)
        pv.x = (float)hd[0]; pv.y = (float)hd[1];
        pv.z = (float)hd[2]; pv.w = (float)hd[3];
    } else {
        pv = *(const float4*)(out + o);              // h_dst f32 (tier small)
    }

    f32x4 g = (f32x4){0.f, 0.f, 0.f, 0.f};
    const _Float16* hl = h_src + lane * 4;

    if (deg > 0 && deg <= 64) {
        f16x4 adv4 = *(const f16x4*)(a_dstH + (size_t)node * 4);
        float ad0 = (float)adv4[0], ad1 = (float)adv4[1];
        float ad2 = (float)adv4[2], ad3 = (float)adv4[3];
        bool act = lane < deg;
        int s = 0;
        f16x4 av4 = (f16x4){0, 0, 0, 0};
        if (act) {
            s = src[r0 + lane];
            av4 = *(const f16x4*)(a_srcH + (size_t)s * 4);
        }
        float e0 = (float)av4[0] + ad0; e0 = e0 > 0.f ? e0 : NEG_SLOPE * e0;
        float e1 = (float)av4[1] + ad1; e1 = e1 > 0.f ? e1 : NEG_SLOPE * e1;
        float e2 = (float)av4[2] + ad2; e2 = e2 > 0.f ? e2 : NEG_SLOPE * e2;
        float e3 = (float)av4[3] + ad3; e3 = e3 > 0.f ? e3 : NEG_SLOPE * e3;
        if (!act) { e0 = e1 = e2 = e3 = -1e30f; }
        float m0 = e0, m1 = e1, m2 = e2, m3 = e3;
        for (int off = 1; off < deg; off <<= 1) {    // adaptive butterfly
            m0 = fmaxf(m0, __shfl_xor(m0, off));
            m1 = fmaxf(m1, __shfl_xor(m1, off));
            m2 = fmaxf(m2, __shfl_xor(m2, off));
            m3 = fmaxf(m3, __shfl_xor(m3, off));
        }
        float w0 = act ? __expf(e0 - m0) : 0.f;
        float w1 = act ? __expf(e1 - m1) : 0.f;
        float w2 = act ? __expf(e2 - m2) : 0.f;
        float w3 = act ? __expf(e3 - m3) : 0.f;
        float d0 = w0, d1 = w1, d2 = w2, d3 = w3;
        for (int off = 1; off < deg; off <<= 1) {
            d0 += __shfl_xor(d0, off); d1 += __shfl_xor(d1, off);
            d2 += __shfl_xor(d2, off); d3 += __shfl_xor(d3, off);
        }
        w0 *= 1.f / d0; w1 *= 1.f / d1; w2 *= 1.f / d2; w3 *= 1.f / d3;
        float4 wv; wv.x = w0; wv.y = w1; wv.z = w2; wv.w = w3;
        *(float4*)&WT[wave][lane][0] = wv;           // same-wave LDS transpose
        asm volatile("s_waitcnt lgkmcnt(0)" ::: "memory");

        int j = 0;
        for (; j + 4 <= deg; j += 4) {               // 4 row-loads in flight (R4)
            int s0 = __builtin_amdgcn_readlane(s, j);
            int s1 = __builtin_amdgcn_readlane(s, j + 1);
            int s2 = __builtin_amdgcn_readlane(s, j + 2);
            int s3 = __builtin_amdgcn_readlane(s, j + 3);
            f16x4 h0 = *(const f16x4*)(hl + (size_t)s0 * 256);
            f16x4 h1 = *(const f16x4*)(hl + (size_t)s1 * 256);
            f16x4 h2 = *(const f16x4*)(hl + (size_t)s2 * 256);
            f16x4 h3 = *(const f16x4*)(hl + (size_t)s3 * 256);
            float x0 = WT[wave][j][head],     x1 = WT[wave][j + 1][head];
            float x2 = WT[wave][j + 2][head], x3 = WT[wave][j + 3][head];
            g[0] += x0 * (float)h0[0]; g[1] += x0 * (float)h0[1];
            g[2] += x0 * (float)h0[2]; g[3] += x0 * (float)h0[3];
            g[0] += x1 * (float)h1[0]; g[1] += x1 * (float)h1[1];
            g[2] += x1 * (float)h1[2]; g[3] += x1 * (float)h1[3];
            g[0] += x2 * (float)h2[0]; g[1] += x2 * (float)h2[1];
            g[2] += x2 * (float)h2[2]; g[3] += x2 * (float)h2[3];
            g[0] += x3 * (float)h3[0]; g[1] += x3 * (float)h3[1];
            g[2] += x3 * (float)h3[2]; g[3] += x3 * (float)h3[3];
        }
        for (; j < deg; ++j) {
            int sj = __builtin_amdgcn_readlane(s, j);
            float xj = WT[wave][j][head];
            f16x4 h = *(const f16x4*)(hl + (size_t)sj * 256);
            g[0] += xj * (float)h[0]; g[1] += xj * (float)h[1];
            g[2] += xj * (float)h[2]; g[3] += xj * (float)h[3];
        }
    } else if (deg > 64) {
        // ---- fallback: chunked 3-pass (deg ~ Poisson(16); essentially never) ----
        f16x4 adv4 = *(const f16x4*)(a_dstH + (size_t)node * 4);
        float ad0 = (float)adv4[0], ad1 = (float)adv4[1];
        float ad2 = (float)adv4[2], ad3 = (float)adv4[3];
        float m0 = -1e30f, m1 = -1e30f, m2 = -1e30f, m3 = -1e30f;
        for (int e = r0 + lane; e < r1; e += 64) {
            int se = src[e];
            f16x4 av4 = *(const f16x4*)(a_srcH + (size_t)se * 4);
            float e0 = (float)av4[0] + ad0; e0 = e0 > 0.f ? e0 : NEG_SLOPE * e0;
            float e1 = (float)av4[1] + ad1; e1 = e1 > 0.f ? e1 : NEG_SLOPE * e1;
            float e2 = (float)av4[2] + ad2; e2 = e2 > 0.f ? e2 : NEG_SLOPE * e2;
            float e3 = (float)av4[3] + ad3; e3 = e3 > 0.f ? e3 : NEG_SLOPE * e3;
            m0 = fmaxf(m0, e0); m1 = fmaxf(m1, e1);
            m2 = fmaxf(m2, e2); m3 = fmaxf(m3, e3);
        }
        #pragma unroll
        for (int off = 32; off > 0; off >>= 1) {
            m0 = fmaxf(m0, __shfl_xor(m0, off)); m1 = fmaxf(m1, __shfl_xor(m1, off));
            m2 = fmaxf(m2, __shfl_xor(m2, off)); m3 = fmaxf(m3, __shfl_xor(m3, off));
        }
        float d0 = 0.f, d1 = 0.f, d2 = 0.f, d3 = 0.f;
        for (int e = r0 + lane; e < r1; e += 64) {
            int se = src[e];
            f16x4 av4 = *(const f16x4*)(a_srcH + (size_t)se * 4);
            float e0 = (float)av4[0] + ad0; e0 = e0 > 0.f ? e0 : NEG_SLOPE * e0;
            float e1 = (float)av4[1] + ad1; e1 = e1 > 0.f ? e1 : NEG_SLOPE * e1;
            float e2 = (float)av4[2] + ad2; e2 = e2 > 0.f ? e2 : NEG_SLOPE * e2;
            float e3 = (float)av4[3] + ad3; e3 = e3 > 0.f ? e3 : NEG_SLOPE * e3;
            d0 += __expf(e0 - m0); d1 += __expf(e1 - m1);
            d2 += __expf(e2 - m2); d3 += __expf(e3 - m3);
        }
        #pragma unroll
        for (int off = 32; off > 0; off >>= 1) {
            d0 += __shfl_xor(d0, off); d1 += __shfl_xor(d1, off);
            d2 += __shfl_xor(d2, off); d3 += __shfl_xor(d3, off);
        }
        float i0 = 1.f / d0, i1 = 1.f / d1, i2 = 1.f / d2, i3 = 1.f / d3;
        for (int c0 = r0; c0 < r1; c0 += 64) {
            int cnt = min(64, r1 - c0);
            int s = 0; float w0 = 0.f, w1 = 0.f, w2 = 0.f, w3 = 0.f;
            if (lane < cnt) {
                s = src[c0 + lane];
                f16x4 av4 = *(const f16x4*)(a_srcH + (size_t)s * 4);
                float e0 = (float)av4[0] + ad0; e0 = e0 > 0.f ? e0 : NEG_SLOPE * e0;
                float e1 = (float)av4[1] + ad1; e1 = e1 > 0.f ? e1 : NEG_SLOPE * e1;
                float e2 = (float)av4[2] + ad2; e2 = e2 > 0.f ? e2 : NEG_SLOPE * e2;
                float e3 = (float)av4[3] + ad3; e3 = e3 > 0.f ? e3 : NEG_SLOPE * e3;
                w0 = __expf(e0 - m0) * i0; w1 = __expf(e1 - m1) * i1;
                w2 = __expf(e2 - m2) * i2; w3 = __expf(e3 - m3) * i3;
            }
            float4 wv; wv.x = w0; wv.y = w1; wv.z = w2; wv.w = w3;
            *(float4*)&WT[wave][lane][0] = wv;
            asm volatile("s_waitcnt lgkmcnt(0)" ::: "memory");
            for (int j = 0; j < cnt; ++j) {
                int sj = __builtin_amdgcn_readlane(s, j);
                float xj = WT[wave][j][head];
                f16x4 h = *(const f16x4*)(hl + (size_t)sj * 256);
                g[0] += xj * (float)h[0]; g[1] += xj * (float)h[1];
                g[2] += xj * (float)h[2]; g[3] += xj * (float)h[3];
            }
        }
    }
    float4 res;
    res.x = pv.x + g[0]; res.y = pv.y + g[1];
    res.z = pv.z + g[2]; res.w = pv.w + g[3];
    *(float4*)(out + o) = res;
}

extern "C" void kernel_launch(void* const* d_in, const int* in_sizes, int n_in,
                              void* d_out, int out_size, void* d_ws, size_t ws_size,
                              hipStream_t stream) {
    const float* feat   = (const float*)d_in[0];
    const float* W_src  = (const float*)d_in[1];
    const float* W_dst  = (const float*)d_in[2];
    const float* b_dst  = (const float*)d_in[3];
    const float* Wa_src = (const float*)d_in[4];
    const float* Wa_dst = (const float*)d_in[5];
    const int*   src    = (const int*)d_in[6];
    const int*   dst    = (const int*)d_in[7];
    float* out = (float*)d_out;
    char* ws = (char*)d_ws;

    // Tier big adds a 51.2 MB f16 h_dst buffer (saves ~100 MB of out RMW
    // traffic); tier small is exactly the R4-proven 53.47 MB layout.
    int useHD = ws_size >= 104670340ull ? 1 : 0;
    _Float16* h_srcH; _Float16* h_dstH;
    unsigned short *Wsw_src, *Wsw_dst, *Wa_sw;
    _Float16 *a_srcH, *a_dstH; int* rp;
    if (useHD) {
        h_srcH  = (_Float16*)(ws);                     // 51,200,000
        h_dstH  = (_Float16*)(ws + 51200000);          // 51,200,000
        Wsw_src = (unsigned short*)(ws + 102400000);   //    131,072
        Wsw_dst = (unsigned short*)(ws + 102531072);   //    131,072
        Wa_sw   = (unsigned short*)(ws + 102662144);   //      8,192
        a_srcH  = (_Float16*)(ws + 102670336);         //    800,000
        a_dstH  = (_Float16*)(ws + 103470336);         //    800,000
        rp      = (int*)(ws + 104270336);              //    400,004
    } else {
        h_srcH  = (_Float16*)(ws);                     // 51,200,000
        h_dstH  = h_srcH;                              // unused
        Wsw_src = (unsigned short*)(ws + 51200000);    //    131,072
        Wsw_dst = (unsigned short*)(ws + 51331072);    //    131,072
        Wa_sw   = (unsigned short*)(ws + 51462144);    //      8,192
        a_srcH  = (_Float16*)(ws + 51470336);          //    800,000
        a_dstH  = (_Float16*)(ws + 52270336);          //    800,000
        rp      = (int*)(ws + 53070336);               //    400,004
    }

    hipLaunchKernelGGL(prep_k,  dim3(919),   dim3(256), 0, stream, W_src, W_dst, Wa_src, Wa_dst,
                       dst, Wsw_src, Wsw_dst, Wa_sw, rp);
    hipLaunchKernelGGL(proja_k, dim3(2345),  dim3(512), 0, stream, feat, Wsw_src, Wsw_dst,
                       Wa_sw, b_dst, h_srcH, h_dstH, useHD, a_srcH, a_dstH, out);
    hipLaunchKernelGGL(agg2_k,  dim3(25000), dim3(256), 0, stream, src, rp, a_srcH, a_dstH,
                       h_srcH, h_dstH, useHD, out);
}